// Round 1
// baseline (393.609 us; speedup 1.0000x reference)
//
#include <hip/hip_runtime.h>

#define ED 128   // embedding dim (== RD)

// One wave (64 lanes) per sample. Each lane owns 2 consecutive floats of the
// 128-dim vectors (float2 loads -> 512B coalesced per row per wave).
//
// Math (collapsed from the reference, eye is the 128x128 identity):
//   h_out = rp_hat * dot(hp_hat, hv_hat) + hv_hat
//   rv_out = rv_hat
//   t_out = rp_hat * dot(tp_hat, tv_hat) + tv_hat
// where x_hat = x * sc_x, sc_x = (||x|| > 1) ? 1/(||x||+1e-7) : 1
// and dot(x_hat, y_hat) = sc_x * sc_y * dot(x, y).

__global__ __launch_bounds__(256) void transd_kernel(
    const float* __restrict__ ent,   // [ENT, 128]
    const float* __restrict__ entp,  // [ENT, 128]
    const float* __restrict__ rel,   // [REL, 128]
    const float* __restrict__ relp,  // [REL, 128]
    const int* __restrict__ h,
    const int* __restrict__ r,
    const int* __restrict__ t,
    float* __restrict__ out,         // [3, B, 128] concat: h_out, rv, t_out
    int B)
{
    const int sample = (blockIdx.x * blockDim.x + threadIdx.x) >> 6;
    const int lane   = threadIdx.x & 63;
    if (sample >= B) return;

    const int hi = h[sample];
    const int ri = r[sample];
    const int ti = t[sample];

    const float2 hp = ((const float2*)(entp + (size_t)hi * ED))[lane];
    const float2 hv = ((const float2*)(ent  + (size_t)hi * ED))[lane];
    const float2 rp = ((const float2*)(relp + (size_t)ri * ED))[lane];
    const float2 rv = ((const float2*)(rel  + (size_t)ri * ED))[lane];
    const float2 tp = ((const float2*)(entp + (size_t)ti * ED))[lane];
    const float2 tv = ((const float2*)(ent  + (size_t)ti * ED))[lane];

    // per-lane partial sums: 6 squared norms + 2 raw dots
    float s_hp = hp.x * hp.x + hp.y * hp.y;
    float s_hv = hv.x * hv.x + hv.y * hv.y;
    float s_rp = rp.x * rp.x + rp.y * rp.y;
    float s_rv = rv.x * rv.x + rv.y * rv.y;
    float s_tp = tp.x * tp.x + tp.y * tp.y;
    float s_tv = tv.x * tv.x + tv.y * tv.y;
    float d_h  = hp.x * hv.x + hp.y * hv.y;
    float d_t  = tp.x * tv.x + tp.y * tv.y;

    // 64-lane butterfly reduction (wave = 64 on CDNA)
    #pragma unroll
    for (int off = 32; off >= 1; off >>= 1) {
        s_hp += __shfl_xor(s_hp, off);
        s_hv += __shfl_xor(s_hv, off);
        s_rp += __shfl_xor(s_rp, off);
        s_rv += __shfl_xor(s_rv, off);
        s_tp += __shfl_xor(s_tp, off);
        s_tv += __shfl_xor(s_tv, off);
        d_h  += __shfl_xor(d_h,  off);
        d_t  += __shfl_xor(d_t,  off);
    }

    auto renorm_scale = [](float s2) -> float {
        float n = sqrtf(s2);
        return (n > 1.0f) ? (1.0f / (n + 1e-7f)) : 1.0f;
    };

    const float sc_hp = renorm_scale(s_hp);
    const float sc_hv = renorm_scale(s_hv);
    const float sc_rp = renorm_scale(s_rp);
    const float sc_rv = renorm_scale(s_rv);
    const float sc_tp = renorm_scale(s_tp);
    const float sc_tv = renorm_scale(s_tv);

    const float dh = d_h * sc_hp * sc_hv;   // dot(hp_hat, hv_hat)
    const float dt = d_t * sc_tp * sc_tv;   // dot(tp_hat, tv_hat)
    const float a_rp = sc_rp;               // rp_hat = rp * sc_rp

    float2 h_out, rv_out, t_out;
    h_out.x  = rp.x * a_rp * dh + hv.x * sc_hv;
    h_out.y  = rp.y * a_rp * dh + hv.y * sc_hv;
    rv_out.x = rv.x * sc_rv;
    rv_out.y = rv.y * sc_rv;
    t_out.x  = rp.x * a_rp * dt + tv.x * sc_tv;
    t_out.y  = rp.y * a_rp * dt + tv.y * sc_tv;

    const size_t row = (size_t)sample * 64 + lane;      // in float2 units
    const size_t sect = (size_t)B * 64;                 // one output section
    float2* o = (float2*)out;
    o[row]            = h_out;
    o[sect + row]     = rv_out;
    o[2 * sect + row] = t_out;
}

extern "C" void kernel_launch(void* const* d_in, const int* in_sizes, int n_in,
                              void* d_out, int out_size, void* d_ws, size_t ws_size,
                              hipStream_t stream) {
    const float* ent  = (const float*)d_in[0];
    const float* entp = (const float*)d_in[1];
    const float* rel  = (const float*)d_in[2];
    const float* relp = (const float*)d_in[3];
    const int*   h    = (const int*)d_in[4];
    const int*   r    = (const int*)d_in[5];
    const int*   t    = (const int*)d_in[6];
    float* out = (float*)d_out;

    const int B = in_sizes[4];           // 8192
    const int samples_per_block = 4;     // 256 threads = 4 waves
    const int grid = (B + samples_per_block - 1) / samples_per_block;
    transd_kernel<<<grid, 256, 0, stream>>>(ent, entp, rel, relp, h, r, t, out, B);
}